// Round 7
// baseline (110.143 us; speedup 1.0000x reference)
//
#include <hip/hip_runtime.h>
#include <math.h>

// Exact IEEE semantics in the visibility path: no fma contraction anywhere.
#pragma clang fp contract(off)

#define IMG 128
#define HW (IMG * IMG)
#define NB 2
#define NV 1300
#define NF 2500
#define NFACE (NB * NF) // 5000
#define EPSF 1e-8f
#define MAXTASK 80000   // exact max: 5000 faces x 16 bands
#define NWAVE 4096      // persistent raster waves (1024 blocks x 4)

// ws layout (bytes):
//   vn    f32[NB*NV*3]   @ 0       (31200)   zeroed by memset (with cnt)
//   cnt   int            @ 31232   (4)
//   face  f4 [NFACE*3]   @ 31744   (240000)  {E0, E1, {area,z0,z1,z2}}
//   rect  i4 [NFACE]     @ 271744  (80000)   {cmin,cmax,rmin,rmax}
//   task  u32[MAXTASK]   @ 351744  (320000)  i | (band<<16)
//   dbuf  u64[NB*HW]     @ 671744  (262144)  memset 0xFF (= +inf sentinel)
#define OFF_CNT 31232
#define OFF_FACE 31744
#define OFF_RECT 271744
#define OFF_TASK 351744
#define OFF_DBUF 671744

__global__ __launch_bounds__(256) void k_face(const float* __restrict__ verts,
                                              const int* __restrict__ faces,
                                              float* __restrict__ vn,
                                              float4* __restrict__ face,
                                              int4* __restrict__ rect,
                                              unsigned* __restrict__ task,
                                              int* __restrict__ cnt) {
    int i = blockIdx.x * 256 + threadIdx.x;
    int lane = threadIdx.x & 63;
    bool act = i < NFACE;
    int nb = 0;
    int cmin = 0, cmax = 0, rmin = 0, rmax = 0;
    if (act) {
        int b = (i >= NF) ? 1 : 0;
        int f = i - b * NF;
        int i0 = faces[f * 3 + 0];
        int i1 = faces[f * 3 + 1];
        int i2 = faces[f * 3 + 2];
        const float* wv = verts + (size_t)b * NV * 3;
        float v0x = wv[i0 * 3 + 0], v0y = wv[i0 * 3 + 1], v0z = wv[i0 * 3 + 2];
        float v1x = wv[i1 * 3 + 0], v1y = wv[i1 * 3 + 1], v1z = wv[i1 * 3 + 2];
        float v2x = wv[i2 * 3 + 0], v2y = wv[i2 * 3 + 1], v2z = wv[i2 * 3 + 2];
        // transform, bit-identical to ref: ndc = (12*(-vx))/(2-vz), z = 2-vz
        float z0 = 2.0f - v0z, z1 = 2.0f - v1z, z2 = 2.0f - v2z;
        float p0x = (12.0f * (-v0x)) / z0, p0y = (12.0f * v0y) / z0;
        float p1x = (12.0f * (-v1x)) / z1, p1y = (12.0f * v1y) / z1;
        float p2x = (12.0f * (-v2x)) / z2, p2y = (12.0f * v2y) / z2;

        float t1 = (p1x - p0x) * (p2y - p0y);
        float t2 = (p1y - p0y) * (p2x - p0x);
        float area = t1 - t2;
        float aabs = fabsf(area);
        float area_safe = (aabs < EPSF) ? EPSF : area;

        face[i * 3 + 0] = make_float4(p2x - p1x, p2y - p1y, p1x, p1y);
        face[i * 3 + 1] = make_float4(p0x - p2x, p0y - p2y, p2x, p2y);
        face[i * 3 + 2] = make_float4(area_safe, z0, z1, z2);

        if (aabs > EPSF) {
            float minx = fminf(p0x, fminf(p1x, p2x));
            float maxx = fmaxf(p0x, fmaxf(p1x, p2x));
            float miny = fminf(p0y, fminf(p1y, p2y));
            float maxy = fmaxf(p0y, fmaxf(p1y, p2y));
            // pixel c: px = 1-(2c+1)/128 (decreasing); c(px=X) = (1-X)*64-0.5
            int ci0 = (int)floorf((1.0f - maxx) * 64.0f - 0.5f) - 1;
            int ci1 = (int)floorf((1.0f - minx) * 64.0f - 0.5f) + 1;
            int ri0 = (int)floorf((1.0f - maxy) * 64.0f - 0.5f) - 1;
            int ri1 = (int)floorf((1.0f - miny) * 64.0f - 0.5f) + 1;
            if (ci1 >= 0 && ci0 <= 127 && ri1 >= 0 && ri0 <= 127) {
                cmin = max(ci0, 0); cmax = min(ci1, 127);
                rmin = max(ri0, 0); rmax = min(ri1, 127);
                nb = ((rmax - rmin) >> 3) + 1; // <= 16
            }
        }
        rect[i] = make_int4(cmin, cmax, rmin, rmax);

        // world-space face normal -> scatter to vertex normals
        float ax = v1x - v0x, ay = v1y - v0y, az = v1z - v0z;
        float bx = v2x - v0x, by = v2y - v0y, bz = v2z - v0z;
        float fnx = ay * bz - az * by;
        float fny = az * bx - ax * bz;
        float fnz = ax * by - ay * bx;
        float* vnb = vn + (size_t)b * NV * 3;
        atomicAdd(&vnb[i0 * 3 + 0], fnx);
        atomicAdd(&vnb[i0 * 3 + 1], fny);
        atomicAdd(&vnb[i0 * 3 + 2], fnz);
        atomicAdd(&vnb[i1 * 3 + 0], fnx);
        atomicAdd(&vnb[i1 * 3 + 1], fny);
        atomicAdd(&vnb[i1 * 3 + 2], fnz);
        atomicAdd(&vnb[i2 * 3 + 0], fnx);
        atomicAdd(&vnb[i2 * 3 + 1], fny);
        atomicAdd(&vnb[i2 * 3 + 2], fnz);
    }
    // wave-aggregated task push: inclusive shfl-scan of nb, 1 atomic per wave
    int incl = nb;
    for (int d = 1; d < 64; d <<= 1) {
        int v = __shfl_up(incl, d, 64);
        if (lane >= d) incl += v;
    }
    int wtot = __shfl(incl, 63, 64);
    int wbase = 0;
    if (lane == 0 && wtot > 0) wbase = atomicAdd(cnt, wtot);
    wbase = __shfl(wbase, 0, 64);
    int my0 = wbase + incl - nb;
    for (int k = 0; k < nb; ++k) task[my0 + k] = (unsigned)i | ((unsigned)k << 16);
}

// Face-stationary rasterizer: each wave grabs tasks (face, 8-row band) from
// the compacted list and sweeps the face's pixel rect in 8x8 lane-tiles.
// No LDS, no syncthreads; depth merge via u64 atomicMin (order-independent,
// ties -> lowest face index, matching ref argmin).
__global__ __launch_bounds__(256) void k_raster(const float4* __restrict__ face,
                                                const int4* __restrict__ rect,
                                                const unsigned* __restrict__ task,
                                                const int* __restrict__ cnt,
                                                unsigned long long* __restrict__ dbuf) {
    int lane = threadIdx.x & 63;
    int wave = blockIdx.x * 4 + (threadIdx.x >> 6);
    int n = *cnt;
    int lr = lane >> 3, lc = lane & 7;
    for (int t = wave; t < n; t += NWAVE) {
        unsigned tk = task[t];
        int i = (int)(tk & 0xFFFFu);
        int band = (int)(tk >> 16);
        int4 rc = rect[i];
        float4 E0 = face[i * 3 + 0];
        float4 E1 = face[i * 3 + 1];
        float4 FD = face[i * 3 + 2];
        int b = (i >= NF) ? 1 : 0;
        int f = i - b * NF;
        float as = FD.x;
        int r = rc.z + (band << 3) + lr;
        bool vr = (r <= rc.w);
        float py = 1.0f - (2.0f * (float)r + 1.0f) / 128.0f;
        unsigned long long* db = dbuf + (size_t)b * HW;
        for (int cb = rc.x; cb <= rc.y; cb += 8) {
            int c = cb + lc;
            bool v = vr && (c <= rc.y);
            float px = 1.0f - (2.0f * (float)c + 1.0f) / 128.0f;
            // exact ref order: e = (bx-ax)*(py-ay) - (by-ay)*(px-ax)
            float u1 = E0.x * (py - E0.w);
            float u2 = E0.y * (px - E0.z);
            float e0 = u1 - u2;
            float u3 = E1.x * (py - E1.w);
            float u4 = E1.y * (px - E1.z);
            float e1 = u3 - u4;
            bool ok = v && ((as > 0.0f) ? (e0 >= 0.0f && e1 >= 0.0f)
                                        : (e0 <= 0.0f && e1 <= 0.0f));
            if (__any(ok)) {
                float b0 = e0 / as; // true IEEE division, as in ref
                float b1 = e1 / as;
                float b2 = (1.0f - b0) - b1;
                float S = ((b0 / FD.y) + (b1 / FD.z)) + (b2 / FD.w);
                if (ok && b2 >= 0.0f && S > EPSF) {
                    float depth = 1.0f / fmaxf(S, EPSF);
                    unsigned long long pk =
                        ((unsigned long long)__float_as_uint(depth) << 32) | (unsigned)f;
                    atomicMin(&db[r * IMG + c], pk);
                }
            }
        }
    }
}

__global__ __launch_bounds__(256) void k_shade(const float* __restrict__ verts,
                                               const int* __restrict__ faces,
                                               const float* __restrict__ vn,
                                               const unsigned long long* __restrict__ dbuf,
                                               float* __restrict__ out) {
    int i = blockIdx.x * 256 + threadIdx.x; // 0..NB*HW-1
    int b = i >> 14;
    int p = i & (HW - 1);
    unsigned long long pk = dbuf[i];
    unsigned dbits = (unsigned)(pk >> 32);
    bool hit = dbits < 0x7F800000u;
    float cr = 255.0f, cg = 255.0f, cb = 255.0f, alpha = 0.0f;
    if (hit) {
        alpha = 1.0f;
        int f = (int)(unsigned)(pk & 0xFFFFFFFFull);
        int row = p >> 7;
        int col = p & 127;
        float px = 1.0f - (2.0f * (float)col + 1.0f) / 128.0f;
        float py = 1.0f - (2.0f * (float)row + 1.0f) / 128.0f;
        int i0 = faces[f * 3 + 0];
        int i1 = faces[f * 3 + 1];
        int i2 = faces[f * 3 + 2];
        const float* wv = verts + (size_t)b * NV * 3;
        float v0x = wv[i0 * 3 + 0], v0y = wv[i0 * 3 + 1], v0z = wv[i0 * 3 + 2];
        float v1x = wv[i1 * 3 + 0], v1y = wv[i1 * 3 + 1], v1z = wv[i1 * 3 + 2];
        float v2x = wv[i2 * 3 + 0], v2y = wv[i2 * 3 + 1], v2z = wv[i2 * 3 + 2];
        float z0 = 2.0f - v0z, z1 = 2.0f - v1z, z2 = 2.0f - v2z;
        float a0x = (12.0f * (-v0x)) / z0, a0y = (12.0f * v0y) / z0;
        float a1x = (12.0f * (-v1x)) / z1, a1y = (12.0f * v1y) / z1;
        float a2x = (12.0f * (-v2x)) / z2, a2y = (12.0f * v2y) / z2;

        float t1 = (a1x - a0x) * (a2y - a0y);
        float t2 = (a1y - a0y) * (a2x - a0x);
        float ar = t1 - t2;
        ar = (fabsf(ar) < EPSF) ? EPSF : ar;
        float u1 = (a2x - a1x) * (py - a1y);
        float u2 = (a2y - a1y) * (px - a1x);
        float bb0 = (u1 - u2) / ar;
        float u3 = (a0x - a2x) * (py - a2y);
        float u4 = (a0y - a2y) * (px - a2x);
        float bb1 = (u3 - u4) / ar;
        float bb2 = (1.0f - bb0) - bb1;
        float w0 = bb0 / z0;
        float w1 = bb1 / z1;
        float w2 = bb2 / z2;
        float denom = ((w0 + w1) + w2) + EPSF;
        float pc0 = w0 / denom;
        float pc1 = w1 / denom;
        float pc2 = w2 / denom;

        float posx = (pc0 * v0x + pc1 * v1x) + pc2 * v2x;
        float posy = (pc0 * v0y + pc1 * v1y) + pc2 * v2y;
        float posz = (pc0 * v0z + pc1 * v1z) + pc2 * v2z;

        const float* vnb = vn + (size_t)b * NV * 3;
        float n0x = vnb[i0 * 3 + 0], n0y = vnb[i0 * 3 + 1], n0z = vnb[i0 * 3 + 2];
        float n1x = vnb[i1 * 3 + 0], n1y = vnb[i1 * 3 + 1], n1z = vnb[i1 * 3 + 2];
        float n2x = vnb[i2 * 3 + 0], n2y = vnb[i2 * 3 + 1], n2z = vnb[i2 * 3 + 2];
        float in0 = 1.0f / (sqrtf(n0x * n0x + n0y * n0y + n0z * n0z) + EPSF);
        float in1 = 1.0f / (sqrtf(n1x * n1x + n1y * n1y + n1z * n1z) + EPSF);
        float in2 = 1.0f / (sqrtf(n2x * n2x + n2y * n2y + n2z * n2z) + EPSF);
        n0x *= in0; n0y *= in0; n0z *= in0;
        n1x *= in1; n1y *= in1; n1z *= in1;
        n2x *= in2; n2y *= in2; n2z *= in2;
        float nx = (pc0 * n0x + pc1 * n1x) + pc2 * n2x;
        float ny = (pc0 * n0y + pc1 * n1y) + pc2 * n2y;
        float nz = (pc0 * n0z + pc1 * n1z) + pc2 * n2z;
        float inn = 1.0f / (sqrtf(nx * nx + ny * ny + nz * nz) + EPSF);
        nx *= inn; ny *= inn; nz *= inn;

        float lx = 0.0f - posx, ly = 1.0f - posy, lz = 3.0f - posz;
        float iln = 1.0f / (sqrtf(lx * lx + ly * ly + lz * lz) + EPSF);
        lx *= iln; ly *= iln; lz *= iln;
        float vx = 0.0f - posx, vy = 0.0f - posy, vz = 2.0f - posz;
        float ivn = 1.0f / (sqrtf(vx * vx + vy * vy + vz * vz) + EPSF);
        vx *= ivn; vy *= ivn; vz *= ivn;

        float ndl = nx * lx + ny * ly + nz * lz;
        float ndlr = fmaxf(ndl, 0.0f);
        float rx = 2.0f * ndl * nx - lx;
        float ry = 2.0f * ndl * ny - ly;
        float rz = 2.0f * ndl * nz - lz;
        float sc = fmaxf(rx * vx + ry * vy + rz * vz, 0.0f);
        float spec = 0.2f * 0.6f * powf(sc, 10.0f);
        float shade = 0.5f * 1.0f + 0.3f * 1.0f * ndlr;
        cr = ((142.0f / 255.0f) * shade + spec) * 255.0f;
        cg = ((179.0f / 255.0f) * shade + spec) * 255.0f;
        cb = ((247.0f / 255.0f) * shade + spec) * 255.0f;
    }
    float* img = out + (size_t)b * 3 * HW;
    img[0 * HW + p] = cr;
    img[1 * HW + p] = cg;
    img[2 * HW + p] = cb;
    out[(size_t)NB * 3 * HW + (size_t)b * HW + p] = alpha;
}

extern "C" void kernel_launch(void* const* d_in, const int* in_sizes, int n_in,
                              void* d_out, int out_size, void* d_ws, size_t ws_size,
                              hipStream_t stream) {
    const float* verts = (const float*)d_in[0]; // [NB, NV, 3]
    const int* faces = (const int*)d_in[1];     // [NF, 3]
    char* ws = (char*)d_ws;
    float* vn = (float*)(ws + 0);
    int* cnt = (int*)(ws + OFF_CNT);
    float4* face = (float4*)(ws + OFF_FACE);
    int4* rect = (int4*)(ws + OFF_RECT);
    unsigned* task = (unsigned*)(ws + OFF_TASK);
    unsigned long long* dbuf = (unsigned long long*)(ws + OFF_DBUF);
    float* out = (float*)d_out;

    hipMemsetAsync(ws, 0, OFF_CNT + 4, stream);                      // vn + cnt
    hipMemsetAsync(ws + OFF_DBUF, 0xFF, NB * HW * 8, stream);        // depth sentinel
    k_face<<<(NFACE + 255) / 256, 256, 0, stream>>>(verts, faces, vn, face, rect, task, cnt);
    k_raster<<<NWAVE / 4, 256, 0, stream>>>(face, rect, task, cnt, dbuf);
    k_shade<<<(NB * HW) / 256, 256, 0, stream>>>(verts, faces, vn, dbuf, out);
}